// Round 3
// baseline (471.426 us; speedup 1.0000x reference)
//
#include <hip/hip_runtime.h>
#include <hip/hip_bf16.h>

// Problem constants (from reference):
//   N=50000 nodes, E=1600000 edges, D=3, IN=32, OUT=32, KS=4, K=64, S=8
// Input dtypes: features/pseudo/weight/bias = float32, edge_index = int32.
// Output dtype: float32 (reference returns fp32; harness compares after
// rounding ref to bf16, threshold = 2% of max|ref| = 1.147e-3).
#define NN 50000
#define EE 1600000
// Z layout: [n][k][o]  (n*2048 + k*32 + o), bf16 (205 MB — fits Infinity Cache)

static __device__ __forceinline__ float b2f(__hip_bfloat16 x) { return __bfloat162float(x); }

// ---------------------------------------------------------------------------
// Z[n,k,o] = sum_i f[n,i] * W[k,i,o]   (fp32 accumulate, bf16 store)
// Block: 256 threads, covers 64 nodes x all 64 k.
// W staged through LDS in tiles of 8 k-matrices; 8 nodes x 8 k per thread.
// ---------------------------------------------------------------------------
__global__ __launch_bounds__(256) void build_z(const float* __restrict__ f,
                                               const float* __restrict__ W,
                                               __hip_bfloat16* __restrict__ Z) {
  __shared__ float fL[64][32];      // 8 KB
  __shared__ float WL[8][32][32];   // 32 KB
  const int t = threadIdx.x;
  const int nb = blockIdx.x * 64;

  for (int idx = t; idx < 64 * 32; idx += 256) {
    int n = idx >> 5, i = idx & 31;
    int gn = nb + n;
    fL[n][i] = (gn < NN) ? f[gn * 32 + i] : 0.0f;
  }

  const int o = t & 31;   // output channel
  const int g = t >> 5;   // node group 0..7 -> nodes g*8..g*8+7

  for (int kt = 0; kt < 8; ++kt) {
    __syncthreads();  // fL ready (kt=0); WL from previous iter fully consumed
    for (int idx = t; idx < 8 * 32 * 32; idx += 256) {
      ((float*)WL)[idx] = W[kt * 8192 + idx];
    }
    __syncthreads();

    float acc[8][8];
#pragma unroll
    for (int j = 0; j < 8; ++j)
#pragma unroll
      for (int kk = 0; kk < 8; ++kk) acc[j][kk] = 0.0f;

#pragma unroll 4
    for (int i = 0; i < 32; ++i) {
      float wv[8], fv[8];
#pragma unroll
      for (int kk = 0; kk < 8; ++kk) wv[kk] = WL[kk][i][o];   // broadcast across g
#pragma unroll
      for (int j = 0; j < 8; ++j) fv[j] = fL[g * 8 + j][i];   // broadcast across o
#pragma unroll
      for (int j = 0; j < 8; ++j)
#pragma unroll
        for (int kk = 0; kk < 8; ++kk) acc[j][kk] += fv[j] * wv[kk];
    }

#pragma unroll
    for (int j = 0; j < 8; ++j) {
      int gn = nb + g * 8 + j;
      if (gn < NN) {
#pragma unroll
        for (int kk = 0; kk < 8; ++kk) {
          Z[(size_t)gn * 2048 + (size_t)(kt * 8 + kk) * 32 + o] = __float2bfloat16(acc[j][kk]);
        }
      }
    }
  }
}

// ---------------------------------------------------------------------------
// Spline basis helper (degree-1, KS=4, D=3): returns 8 weights + base index.
// ---------------------------------------------------------------------------
static __device__ __forceinline__ void spline_basis(const float* __restrict__ pseudo,
                                                    int e, float w[8], int& base) {
  float v0 = pseudo[e * 3 + 0] * 3.0f;
  float v1 = pseudo[e * 3 + 1] * 3.0f;
  float v2 = pseudo[e * 3 + 2] * 3.0f;
  float b0 = fmaxf(fminf(floorf(v0), 2.0f), 0.0f);
  float b1 = fmaxf(fminf(floorf(v1), 2.0f), 0.0f);
  float b2 = fmaxf(fminf(floorf(v2), 2.0f), 0.0f);
  float f0 = v0 - b0, f1 = v1 - b1, f2 = v2 - b2;
  float g0 = 1.0f - f0, g1 = 1.0f - f1, g2 = 1.0f - f2;
  base = (int)b0 + 4 * (int)b1 + 16 * (int)b2;
  w[0] = g0 * g1 * g2; w[1] = f0 * g1 * g2;
  w[2] = g0 * f1 * g2; w[3] = f0 * f1 * g2;
  w[4] = g0 * g1 * f2; w[5] = f0 * g1 * f2;
  w[6] = g0 * f1 * f2; w[7] = f0 * f1 * f2;
}

// flat-index offsets of the 8 basis combos relative to base (x32 channels)
__constant__ int kOffs[8] = {0, 1, 4, 5, 16, 17, 20, 21};

// ---------------------------------------------------------------------------
// Main path: per-edge gather of 8 rows of Z[col], weighted sum, atomic
// scatter into fp32 accumulator at target row. 32 lanes per edge (lane = o).
// ---------------------------------------------------------------------------
__global__ __launch_bounds__(256) void edge_msg(const float* __restrict__ pseudo,
                                                const int* __restrict__ ei,
                                                const __hip_bfloat16* __restrict__ Z,
                                                float* __restrict__ acc,
                                                float* __restrict__ deg) {
  const int tid = blockIdx.x * 256 + threadIdx.x;
  const int e = tid >> 5;
  const int o = tid & 31;
  if (e >= EE) return;

  const int row = ei[e];        // target
  const int col = ei[EE + e];   // source

  float w[8]; int base;
  spline_basis(pseudo, e, w, base);

  const __hip_bfloat16* zp = Z + (size_t)col * 2048 + (size_t)base * 32 + o;
  float a = 0.0f;
  a += w[0] * b2f(zp[0]);
  a += w[1] * b2f(zp[32]);
  a += w[2] * b2f(zp[128]);
  a += w[3] * b2f(zp[160]);
  a += w[4] * b2f(zp[512]);
  a += w[5] * b2f(zp[544]);
  a += w[6] * b2f(zp[640]);
  a += w[7] * b2f(zp[672]);

  atomicAdd(acc + (size_t)row * 32 + o, a);
  if (o == 0) atomicAdd(deg + row, 1.0f);
}

// ---------------------------------------------------------------------------
// Fallback path (small workspace): no Z — compute msg directly from f and W.
// a_o = sum_i f[col,i] * (sum_s w_s * W[flat_s, i, o])
// ---------------------------------------------------------------------------
__global__ __launch_bounds__(256) void edge_direct(const float* __restrict__ pseudo,
                                                   const int* __restrict__ ei,
                                                   const float* __restrict__ f,
                                                   const float* __restrict__ W,
                                                   float* __restrict__ acc,
                                                   float* __restrict__ deg) {
  const int tid = blockIdx.x * 256 + threadIdx.x;
  const int e = tid >> 5;
  const int o = tid & 31;
  if (e >= EE) return;

  const int row = ei[e];
  const int col = ei[EE + e];

  float w[8]; int base;
  spline_basis(pseudo, e, w, base);

  const float myf = f[col * 32 + o];
  float a = 0.0f;
  for (int i = 0; i < 32; ++i) {
    float fi = __shfl(myf, i, 32);
    float wsum = 0.0f;
#pragma unroll
    for (int s = 0; s < 8; ++s) {
      wsum += w[s] * W[(size_t)(base + kOffs[s]) * 1024 + i * 32 + o];
    }
    a += fi * wsum;
  }

  atomicAdd(acc + (size_t)row * 32 + o, a);
  if (o == 0) atomicAdd(deg + row, 1.0f);
}

// ---------------------------------------------------------------------------
// out[n,o] = acc[n,o] / max(deg[n],1) + bias[o]   (fp32 store)
// ---------------------------------------------------------------------------
__global__ __launch_bounds__(256) void finalize(const float* __restrict__ acc,
                                                const float* __restrict__ deg,
                                                const float* __restrict__ bias,
                                                float* __restrict__ out) {
  int tid = blockIdx.x * 256 + threadIdx.x;
  if (tid >= NN * 32) return;
  int n = tid >> 5, o = tid & 31;
  float d = fmaxf(deg[n], 1.0f);
  out[tid] = acc[tid] / d + bias[o];
}

extern "C" void kernel_launch(void* const* d_in, const int* in_sizes, int n_in,
                              void* d_out, int out_size, void* d_ws, size_t ws_size,
                              hipStream_t stream) {
  const float* f      = (const float*)d_in[0];
  const float* pseudo = (const float*)d_in[1];
  const float* W      = (const float*)d_in[2];
  const float* bias   = (const float*)d_in[3];
  const int*   ei     = (const int*)d_in[4];
  float* out = (float*)d_out;

  const size_t zBytes = (size_t)NN * 2048 * 2;   // 204,800,000
  const size_t accBytes = (size_t)NN * 32 * 4;   //   6,400,000
  const size_t degBytes = (size_t)NN * 4;        //     200,000

  if (ws_size >= zBytes + accBytes + degBytes) {
    // Main path: precompute Z[n,k,o] in bf16 (fits Infinity Cache).
    char* ws = (char*)d_ws;
    __hip_bfloat16* Z = (__hip_bfloat16*)ws;
    float* acc = (float*)(ws + zBytes);
    float* deg = (float*)(ws + zBytes + accBytes);
    hipMemsetAsync(acc, 0, accBytes + degBytes, stream);
    build_z<<<(NN + 63) / 64, 256, 0, stream>>>(f, W, Z);
    edge_msg<<<(EE * 32) / 256, 256, 0, stream>>>(pseudo, ei, Z, acc, deg);
    finalize<<<(NN * 32) / 256, 256, 0, stream>>>(acc, deg, bias, out);
  } else {
    // Fallback: direct per-edge compute; workspace needs only acc+deg.
    char* ws = (char*)d_ws;
    float* acc = (float*)ws;
    float* deg = (float*)(ws + accBytes);
    hipMemsetAsync(acc, 0, accBytes + degBytes, stream);
    edge_direct<<<(EE * 32) / 256, 256, 0, stream>>>(pseudo, ei, f, W, acc, deg);
    finalize<<<(NN * 32) / 256, 256, 0, stream>>>(acc, deg, bias, out);
  }
}

// Round 4
// 400.585 us; speedup vs baseline: 1.1768x; 1.1768x over previous
//
#include <hip/hip_runtime.h>
#include <hip/hip_bf16.h>

// Problem constants: N=50000, E=1600000, D=3, IN=32, OUT=32, KS=4, K=64, S=8
// Inputs fp32 (+ int32 edge_index); output fp32; Z intermediate bf16 (205 MB).
#define NN 50000
#define EE 1600000
// Z layout: [n][k][o]  (n*2048 + k*32 + o), bf16

typedef __attribute__((ext_vector_type(8))) short  s16x8;   // 8 bf16 (4 VGPRs) — MFMA A/B frag
typedef __attribute__((ext_vector_type(4))) float  f32x4;   // MFMA C/D frag

static __device__ __forceinline__ float b2f(__hip_bfloat16 x) { return __bfloat162float(x); }
static __device__ __forceinline__ short f2bs(float x) {
  __hip_bfloat16 h = __float2bfloat16(x);
  short s; __builtin_memcpy(&s, &h, 2); return s;
}

// ---------------------------------------------------------------------------
// Pack W (fp32 [k][i][o], 512 KB) into bf16 MFMA B-fragment layout:
// B[k][c] = W[c>>5][k][c&31],  c = column = kmat*32+o  (2048 cols, K=32 rows).
// Frag elem (tile t, lane l, j): B[k=(l>>4)*8+j][c=t*16+(l&15)].
// Wb: 128 tiles * 64 lanes * 8 bf16 = 128 KB.
// ---------------------------------------------------------------------------
__global__ __launch_bounds__(256) void conv_w(const float* __restrict__ W,
                                              short* __restrict__ Wb) {
  int tid = blockIdx.x * 256 + threadIdx.x;       // 8192 threads
  if (tid >= 128 * 64) return;
  int t = tid >> 6, l = tid & 63;
  int c = t * 16 + (l & 15);
  int k0 = (l >> 4) * 8;
  s16x8 frag;
#pragma unroll
  for (int j = 0; j < 8; ++j) {
    frag[j] = f2bs(W[(c >> 5) * 1024 + (k0 + j) * 32 + (c & 31)]);
  }
  ((s16x8*)Wb)[tid] = frag;
}

// ---------------------------------------------------------------------------
// Z[n][c] = sum_i f[n][i] * B[i][c]  via mfma_f32_16x16x32_bf16 (K=32=IN_F).
// Grid: 3125 blocks (16 nodes each), 4 waves/block; wave w covers c-tiles
// [w*32, w*32+32). A-frag: A[m=lane&15][k=(lane>>4)*8+j] from f (fp32->bf16).
// D: col=lane&15 (channel), row=(lane>>4)*4+reg (node)  [m89-verified layout].
// ---------------------------------------------------------------------------
__global__ __launch_bounds__(256) void build_z_mfma(const float* __restrict__ f,
                                                    const short* __restrict__ Wb,
                                                    __hip_bfloat16* __restrict__ Z) {
  const int l = threadIdx.x & 63;
  const int w = threadIdx.x >> 6;
  const int n0 = blockIdx.x * 16;

  const int m  = l & 15;          // A row (node) for loading
  const int kb = (l >> 4) * 8;    // A k-block

  const f32x4* fp = (const f32x4*)(f + (size_t)(n0 + m) * 32 + kb);
  f32x4 a0 = fp[0], a1 = fp[1];
  s16x8 afrag;
#pragma unroll
  for (int j = 0; j < 4; ++j) { afrag[j] = f2bs(a0[j]); afrag[4 + j] = f2bs(a1[j]); }

  const int nch  = l & 15;              // D column (channel within tile)
  const int rowb = n0 + (l >> 4) * 4;   // D row base (node)

#pragma unroll 4
  for (int t = w * 32; t < w * 32 + 32; ++t) {
    s16x8 bfrag = ((const s16x8*)Wb)[t * 64 + l];
    f32x4 d = __builtin_amdgcn_mfma_f32_16x16x32_bf16(afrag, bfrag, (f32x4){0.f, 0.f, 0.f, 0.f}, 0, 0, 0);
    int col = t * 16 + nch;
#pragma unroll
    for (int r = 0; r < 4; ++r) {
      Z[(size_t)(rowb + r) * 2048 + col] = __float2bfloat16(d[r]);
    }
  }
}

// ---------------------------------------------------------------------------
// Spline basis (degree-1, KS=4, D=3): 8 weights + base flat index.
// ---------------------------------------------------------------------------
static __device__ __forceinline__ void spline_basis(const float* __restrict__ pseudo,
                                                    int e, float w[8], int& base) {
  float v0 = pseudo[e * 3 + 0] * 3.0f;
  float v1 = pseudo[e * 3 + 1] * 3.0f;
  float v2 = pseudo[e * 3 + 2] * 3.0f;
  float b0 = fmaxf(fminf(floorf(v0), 2.0f), 0.0f);
  float b1 = fmaxf(fminf(floorf(v1), 2.0f), 0.0f);
  float b2 = fmaxf(fminf(floorf(v2), 2.0f), 0.0f);
  float f0 = v0 - b0, f1 = v1 - b1, f2 = v2 - b2;
  float g0 = 1.0f - f0, g1 = 1.0f - f1, g2 = 1.0f - f2;
  base = (int)b0 + 4 * (int)b1 + 16 * (int)b2;
  w[0] = g0 * g1 * g2; w[1] = f0 * g1 * g2;
  w[2] = g0 * f1 * g2; w[3] = f0 * f1 * g2;
  w[4] = g0 * g1 * f2; w[5] = f0 * g1 * f2;
  w[6] = g0 * f1 * f2; w[7] = f0 * f1 * f2;
}

__constant__ int kOffs[8] = {0, 1, 4, 5, 16, 17, 20, 21};

// ---------------------------------------------------------------------------
// Per-edge gather of 8 rows of Z[col], weighted sum, atomic scatter to acc.
// 32 lanes per edge (lane = output channel).
// ---------------------------------------------------------------------------
__global__ __launch_bounds__(256) void edge_msg(const float* __restrict__ pseudo,
                                                const int* __restrict__ ei,
                                                const __hip_bfloat16* __restrict__ Z,
                                                float* __restrict__ acc,
                                                float* __restrict__ deg) {
  const int tid = blockIdx.x * 256 + threadIdx.x;
  const int e = tid >> 5;
  const int o = tid & 31;
  if (e >= EE) return;

  const int row = ei[e];        // target
  const int col = ei[EE + e];   // source

  float w[8]; int base;
  spline_basis(pseudo, e, w, base);

  const __hip_bfloat16* zp = Z + (size_t)col * 2048 + (size_t)base * 32 + o;
  float a = 0.0f;
  a += w[0] * b2f(zp[0]);
  a += w[1] * b2f(zp[32]);
  a += w[2] * b2f(zp[128]);
  a += w[3] * b2f(zp[160]);
  a += w[4] * b2f(zp[512]);
  a += w[5] * b2f(zp[544]);
  a += w[6] * b2f(zp[640]);
  a += w[7] * b2f(zp[672]);

  atomicAdd(acc + (size_t)row * 32 + o, a);
  if (o == 0) atomicAdd(deg + row, 1.0f);
}

// ---------------------------------------------------------------------------
// Fallback (small workspace): direct per-edge compute from f and W.
// ---------------------------------------------------------------------------
__global__ __launch_bounds__(256) void edge_direct(const float* __restrict__ pseudo,
                                                   const int* __restrict__ ei,
                                                   const float* __restrict__ f,
                                                   const float* __restrict__ W,
                                                   float* __restrict__ acc,
                                                   float* __restrict__ deg) {
  const int tid = blockIdx.x * 256 + threadIdx.x;
  const int e = tid >> 5;
  const int o = tid & 31;
  if (e >= EE) return;

  const int row = ei[e];
  const int col = ei[EE + e];

  float w[8]; int base;
  spline_basis(pseudo, e, w, base);

  const float myf = f[col * 32 + o];
  float a = 0.0f;
  for (int i = 0; i < 32; ++i) {
    float fi = __shfl(myf, i, 32);
    float wsum = 0.0f;
#pragma unroll
    for (int s = 0; s < 8; ++s) {
      wsum += w[s] * W[(size_t)(base + kOffs[s]) * 1024 + i * 32 + o];
    }
    a += fi * wsum;
  }

  atomicAdd(acc + (size_t)row * 32 + o, a);
  if (o == 0) atomicAdd(deg + row, 1.0f);
}

// ---------------------------------------------------------------------------
// out[n,o] = acc[n,o] / max(deg[n],1) + bias[o]
// ---------------------------------------------------------------------------
__global__ __launch_bounds__(256) void finalize(const float* __restrict__ acc,
                                                const float* __restrict__ deg,
                                                const float* __restrict__ bias,
                                                float* __restrict__ out) {
  int tid = blockIdx.x * 256 + threadIdx.x;
  if (tid >= NN * 32) return;
  int n = tid >> 5, o = tid & 31;
  float d = fmaxf(deg[n], 1.0f);
  out[tid] = acc[tid] / d + bias[o];
}

extern "C" void kernel_launch(void* const* d_in, const int* in_sizes, int n_in,
                              void* d_out, int out_size, void* d_ws, size_t ws_size,
                              hipStream_t stream) {
  const float* f      = (const float*)d_in[0];
  const float* pseudo = (const float*)d_in[1];
  const float* W      = (const float*)d_in[2];
  const float* bias   = (const float*)d_in[3];
  const int*   ei     = (const int*)d_in[4];
  float* out = (float*)d_out;

  const size_t zBytes   = (size_t)NN * 2048 * 2;   // 204,800,000
  const size_t accBytes = (size_t)NN * 32 * 4;     //   6,400,000
  const size_t degBytes = (size_t)NN * 4;          //     200,000
  const size_t wbBytes  = 128 * 64 * 8 * 2;        //     131,072

  if (ws_size >= zBytes + accBytes + degBytes) {
    char* ws = (char*)d_ws;
    __hip_bfloat16* Z = (__hip_bfloat16*)ws;
    float* acc = (float*)(ws + zBytes);
    float* deg = (float*)(ws + zBytes + accBytes);
    // Wb (128 KB): tail of ws if it fits, else borrow d_out (6.4 MB, only
    // written by finalize at the very end — safe same-stream scratch).
    short* Wb = (ws_size >= zBytes + accBytes + degBytes + wbBytes)
                    ? (short*)(ws + zBytes + accBytes + degBytes)
                    : (short*)d_out;

    hipMemsetAsync(acc, 0, accBytes + degBytes, stream);
    conv_w<<<32, 256, 0, stream>>>(W, Wb);
    build_z_mfma<<<NN / 16, 256, 0, stream>>>(f, Wb, Z);
    edge_msg<<<(EE * 32) / 256, 256, 0, stream>>>(pseudo, ei, Z, acc, deg);
    finalize<<<(NN * 32) / 256, 256, 0, stream>>>(acc, deg, bias, out);
  } else {
    char* ws = (char*)d_ws;
    float* acc = (float*)ws;
    float* deg = (float*)(ws + accBytes);
    hipMemsetAsync(acc, 0, accBytes + degBytes, stream);
    edge_direct<<<(EE * 32) / 256, 256, 0, stream>>>(pseudo, ei, f, W, acc, deg);
    finalize<<<(NN * 32) / 256, 256, 0, stream>>>(acc, deg, bias, out);
  }
}